// Round 11
// baseline (1119.149 us; speedup 1.0000x reference)
//
#include <hip/hip_runtime.h>
#include <cmath>

typedef __attribute__((ext_vector_type(8))) short short8;
typedef __attribute__((ext_vector_type(4))) float f32x4;
typedef unsigned short u16;

#define NB   16
#define NC   128
#define NS   64
#define NW   64
#define NHH  128
#define GSTR (NHH * NC * 3)

// workspace layout (bytes)
#define WI_OFF   0u          // Wi packed: 512*256*2 = 262144
#define WS_OFF   262144u     // Ws packed: 512*384*2 = 393216 (ends 655360)
#define FLAG_OFF 655360u     // cnt[b*64+s] uint32: 4 KB
#define HX_OFF   786432u     // hx[b][2][64][128] u16 = 512 KB
#define FS_OFF   2097152u    // fs (bias included): 1024*512*64*2 = 67108864
#define WS_NEEDED (FS_OFF + (size_t)NB * NS * 512 * NW * 2)

__device__ __forceinline__ u16 f2bf(float f) {
    unsigned u = __builtin_bit_cast(unsigned, f);
    u += 0x7fffu + ((u >> 16) & 1u);
    return (u16)(u >> 16);
}
__device__ __forceinline__ float bfreg(uint2 u, int r) {
    unsigned w = (r < 2) ? u.x : u.y;
    unsigned bits = (r & 1) ? (w & 0xffff0000u) : (w << 16);
    return __builtin_bit_cast(float, bits);
}
__device__ __forceinline__ float fsig(float x) {
    return __builtin_amdgcn_rcpf(1.f + __builtin_amdgcn_exp2f(x * -1.442695041f));
}
__device__ __forceinline__ float ftanh(float x) {
    return 1.f - 2.f * __builtin_amdgcn_rcpf(1.f + __builtin_amdgcn_exp2f(x * 2.885390082f));
}

// ---------------- phase 0: pack weights into MFMA A-fragment layout (bf16) ----
// Wi: wip[(((W*4+g)*8+kt)*64+l)*8+j],  m=128g+16W+(l&15), k=kt*32+(l>>4)*8+j -> (dy,c)
// Ws: wsp[(((W*4+g)*12+kt)*64+l)*8+j], m=128g+16W+(l&15), k -> (d=k>>7, c=k&127)
__global__ void pack_weights(const float* __restrict__ w_itos,
                             const float* __restrict__ w_stos,
                             u16* __restrict__ wip, u16* __restrict__ wsp) {
    int e = blockIdx.x * 256 + threadIdx.x;
    if (e < 131072) {
        int j = e & 7, l = (e >> 3) & 63, kt = (e >> 9) & 7, wvg = e >> 12;
        int wv = wvg >> 2, g = wvg & 3;
        int m = 128 * g + 16 * wv + (l & 15);
        int k = kt * 32 + (l >> 4) * 8 + j;
        int dy = k >> 7, c = k & 127;
        wip[e] = f2bf(w_itos[(m * 128 + c) * 3 + dy]);   // dy in {0,1}; row 2 masked off
    } else if (e < 327680) {
        int e2 = e - 131072;
        int wvg = e2 / 6144, rem = e2 % 6144;
        int wv = wvg >> 2, g = wvg & 3;
        int kt = rem >> 9, l = (rem >> 3) & 63, j = rem & 7;
        int m = 128 * g + 16 * wv + (l & 15);
        int k = kt * 32 + (l >> 4) * 8 + j;
        int d = k >> 7, c = k & 127;
        wsp[e2] = f2bf(w_stos[(m * 128 + c) * 3 + d]);
    }
}

// ---------------- phase 1: input-to-state conv as bf16 MFMA GEMM --------------
// One block per (b,s). fs INCLUDES b_itos+b_stos. Layout:
// fsp[(bs*8+W)*1024 + (g*4+n)*64 + l], packed bf16 pairs for acc rows r=0..3.
__global__ __launch_bounds__(512, 2) void itos_gemm(
    const float* __restrict__ image, const u16* __restrict__ wip,
    const float* __restrict__ b_itos, const float* __restrict__ b_stos,
    uint2* __restrict__ fsp) {
    const int bs = blockIdx.x, b = bs >> 6, s = bs & 63;
    const int t = threadIdx.x, wv = t >> 6, l = t & 63, lr = l & 15, lk = l >> 4;
    __shared__ u16 ImgT[64 * 256];   // [w][k], k = dy*128+c, XOR-swizzled

    {   // stage rows s-1 (dy=0) and s (dy=1), fp32 -> bf16, transposed
        const int r = t >> 1, half = t & 1;   // r = dy*128 + c
        const int dy = r >> 7, c = r & 127;
        const int s0 = s - 1 + dy;
        float v[32];
        if (s0 >= 0) {
            const float* src = image + (((size_t)b * NC + c) * NS + s0) * NW + half * 32;
            #pragma unroll
            for (int qq = 0; qq < 8; ++qq) {
                float4 f = *(const float4*)(src + 4 * qq);
                v[4*qq] = f.x; v[4*qq+1] = f.y; v[4*qq+2] = f.z; v[4*qq+3] = f.w;
            }
        } else {
            #pragma unroll
            for (int qq = 0; qq < 32; ++qq) v[qq] = 0.f;
        }
        #pragma unroll
        for (int qq = 0; qq < 32; ++qq) {
            int w = half * 32 + qq;
            ImgT[w * 256 + (r ^ ((w & 7) << 3))] = f2bf(v[qq]);
        }
    }
    __syncthreads();

    f32x4 acc[4][4];
    #pragma unroll
    for (int g = 0; g < 4; ++g)
        #pragma unroll
        for (int n = 0; n < 4; ++n) acc[g][n] = (f32x4){0.f, 0.f, 0.f, 0.f};

    #pragma unroll
    for (int kt = 0; kt < 8; ++kt) {
        short8 a[4], bb[4];
        #pragma unroll
        for (int g = 0; g < 4; ++g)
            a[g] = *(const short8*)(wip + (((wv * 4 + g) * 8 + kt) * 64 + l) * 8);
        const int cu = kt * 32 + lk * 8;
        #pragma unroll
        for (int n = 0; n < 4; ++n) {
            const int w = n * 16 + lr;
            bb[n] = *(const short8*)&ImgT[w * 256 + (cu ^ ((w & 7) << 3))];
        }
        #pragma unroll
        for (int g = 0; g < 4; ++g)
            #pragma unroll
            for (int n = 0; n < 4; ++n)
                acc[g][n] = __builtin_amdgcn_mfma_f32_16x16x32_bf16(a[g], bb[n], acc[g][n], 0, 0, 0);
    }

    float bias[4][4];
    #pragma unroll
    for (int g = 0; g < 4; ++g)
        #pragma unroll
        for (int r = 0; r < 4; ++r) {
            int m = 128 * g + 16 * wv + lk * 4 + r;
            bias[g][r] = b_itos[m] + b_stos[m];
        }

    uint2* dst = fsp + ((size_t)bs * 8 + wv) * 1024 + l;
    #pragma unroll
    for (int g = 0; g < 4; ++g)
        #pragma unroll
        for (int n = 0; n < 4; ++n) {
            uint2 u;
            u.x = (unsigned)f2bf(acc[g][n][0] + bias[g][0]) | ((unsigned)f2bf(acc[g][n][1] + bias[g][1]) << 16);
            u.y = (unsigned)f2bf(acc[g][n][2] + bias[g][2]) | ((unsigned)f2bf(acc[g][n][3] + bias[g][3]) << 16);
            dst[(g * 4 + n) * 64] = u;
        }
}

// ---------------- phase 2: recurrent, M-split 4-way, weights in LDS -----------
// 64 blocks: bid = mo*16 + b (a batch's 4 blocks share bid%8 -> same XCD/L2).
// Block mo: nh in [32mo,32mo+32), all 4 gates, all w. 96 KB weight slice staged
// into LDS ONCE -> zero steady-state weight traffic (the R2..R10 bottleneck).
// 8 waves: wv = hh*4+nt. Wave: all gates of 16 nh rows (hh), w-tile nt.
// Gating fully in-wave. h exchanged cross-block via hx + per-step counter
// (machinery byte-identical to R8, which passed).
__global__ __launch_bounds__(512, 2) void rowlstm_ls(
    const u16* __restrict__ wsp, const uint2* __restrict__ fsp,
    const float* __restrict__ h0, const float* __restrict__ c0,
    unsigned* __restrict__ cnt, u16* __restrict__ hx,
    float* __restrict__ out) {
    const int bid = blockIdx.x;
    const int b = bid & 15, mo = bid >> 4;
    const int t = threadIdx.x, wv = t >> 6, l = t & 63, lr = l & 15, lk = l >> 4;
    const int hh = wv >> 2, nt = wv & 3;

    __shared__ u16 lds[49152 + 8448];   // weights 96 KB + Ht [66][128] 16.9 KB
    u16* wlds = lds;
    u16* Ht   = lds + 49152;

    // stage this block's weight slice into LDS (one time):
    // wlds[(mt*12+kt)*512 + l2*8], mt = hh*4+g
    for (int idx = t; idx < 6144; idx += 512) {
        const int mt = idx / 768, rem = idx % 768;   // 768 = 12*64
        const int kt = rem >> 6, l2 = rem & 63;
        const int W = 2 * mo + (mt >> 2), g = mt & 3;
        *(uint4*)&wlds[idx * 8] =
            *(const uint4*)&wsp[(((W * 4 + g) * 12 + kt) * 64 + l2) * 8];
    }

    // Ht halo rows + full h0 fill
    if (t < 256) { int i = t & 127; Ht[((t >> 7) ? 65 : 0) * 128 + i] = 0; }
    #pragma unroll
    for (int j = 0; j < 16; ++j) {
        int e = t * 16 + j, nh = e >> 6, w = e & 63, wh = w + 1;
        Ht[wh * 128 + (nh ^ ((wh & 7) << 3))] = f2bf(h0[e]);
    }

    // per-lane outputs: nh = nh0 + r (r=0..3), w = wE
    const int nh0 = 32 * mo + 16 * hh + lk * 4;
    const int wE  = nt * 16 + lr;
    float c_r[4];
    #pragma unroll
    for (int r = 0; r < 4; ++r) c_r[r] = c0[(nh0 + r) * 64 + wE];
    float* outb = out + ((size_t)b * NHH + nh0) * (NS * NW) + wE;

    const uint2* fsb = fsp + ((size_t)(b * 64) * 8 + 2 * mo + hh) * 1024 + l;

    __syncthreads();

    uint2 fsv[4];
    #pragma unroll
    for (int g = 0; g < 4; ++g) fsv[g] = fsb[(g * 4 + nt) * 64];

    for (int s = 0; s < NS; ++s) {
        const int p = (s + 1) & 1;

        // ---- A: GEMM; acc init from fs (bias folded in) ----
        f32x4 acc[4];
        #pragma unroll
        for (int g = 0; g < 4; ++g)
            #pragma unroll
            for (int r = 0; r < 4; ++r) acc[g][r] = bfreg(fsv[g], r);

        if (s < NS - 1) {   // prefetch next step's fs (in flight through GEMM)
            #pragma unroll
            for (int g = 0; g < 4; ++g)
                fsv[g] = fsb[(size_t)(s + 1) * 8192 + (g * 4 + nt) * 64];
        }

        #pragma unroll
        for (int kt = 0; kt < 12; ++kt) {
            const int d = kt >> 2, kc = kt & 3;
            const int cu = kc * 32 + lk * 8;
            const int wh = wE + d;            // h index = wh-1 = w+d-1
            short8 bb = *(const short8*)&Ht[wh * 128 + (cu ^ ((wh & 7) << 3))];
            #pragma unroll
            for (int g = 0; g < 4; ++g) {
                short8 wA = *(const short8*)&wlds[(((hh * 4 + g) * 12 + kt) * 64 + l) * 8];
                acc[g] = __builtin_amdgcn_mfma_f32_16x16x32_bf16(wA, bb, acc[g], 0, 0, 0);
            }
        }

        // ---- B: in-wave gating epilogue; h_new = c_OLD * sigmoid(o) ----
        u16 hb[4];
        #pragma unroll
        for (int r = 0; r < 4; ++r) {
            const float si = fsig(acc[0][r]);
            const float tg = ftanh(acc[1][r]);
            const float sf = fsig(acc[2][r]);
            const float so = fsig(acc[3][r]);
            const float cold = c_r[r];
            c_r[r] = sf * cold + si * tg;
            const float hn = cold * so;
            outb[(size_t)r * (NS * NW) + s * NW] = hn;
            hb[r] = f2bf(hn);
        }
        {   // own h-slice -> hx (pre-swizzled in Ht layout)
            const int whE = wE + 1;
            uint2 hw;
            hw.x = (unsigned)hb[0] | ((unsigned)hb[1] << 16);
            hw.y = (unsigned)hb[2] | ((unsigned)hb[3] << 16);
            *(uint2*)&hx[(size_t)(b * 2 + p) * 8192 + wE * 128 + (nh0 ^ ((whE & 7) << 3))] = hw;
        }

        if (s < NS - 1) {
            // ---- C: cross-block sync (R8-validated) ----
            __threadfence();
            __syncthreads();
            if (t == 0) {
                unsigned* f = cnt + (b * 64 + s);
                __hip_atomic_fetch_add(f, 1u, __ATOMIC_ACQ_REL, __HIP_MEMORY_SCOPE_AGENT);
                while (__hip_atomic_load(f, __ATOMIC_ACQUIRE, __HIP_MEMORY_SCOPE_AGENT) < 4u) {}
            }
            __syncthreads();
            // ---- D: rebuild Ht from hx (layout-preserving copy) ----
            {
                const int row = t >> 3;
                const int ch  = (t & 7) ^ (row & 7);
                const uint4* src = (const uint4*)&hx[(size_t)(b * 2 + p) * 8192 + row * 128 + ch * 16];
                uint4 v0 = src[0], v1 = src[1];
                *(uint4*)&Ht[(row + 1) * 128 + ch * 16]     = v0;
                *(uint4*)&Ht[(row + 1) * 128 + ch * 16 + 8] = v1;
            }
            asm volatile("s_waitcnt lgkmcnt(0)" ::: "memory");
            __builtin_amdgcn_s_barrier();
            asm volatile("" ::: "memory");
        }
    }
}

// ---------------- fallback (validated round-1 fp32 kernel) --------------------
__global__ __launch_bounds__(512, 2) void rowlstm_f32(
    const float* __restrict__ image, const float* __restrict__ w_itos,
    const float* __restrict__ b_itos, const float* __restrict__ w_stos,
    const float* __restrict__ b_stos, const float* __restrict__ h0,
    const float* __restrict__ c0, float* __restrict__ out) {
    const int b = blockIdx.x, t = threadIdx.x, wq = t & 3, nh = t >> 2, w0 = wq * 16;
    __shared__ float h_lds[NHH][NW + 2];
    #pragma unroll
    for (int j = 0; j < 16; ++j) h_lds[nh][1 + w0 + j] = h0[nh * NW + w0 + j];
    if (wq == 0) { h_lds[nh][0] = 0.f; h_lds[nh][NW + 1] = 0.f; }
    float c_r[16];
    #pragma unroll
    for (int j = 0; j < 16; ++j) c_r[j] = c0[nh * NW + w0 + j];
    const float bias[4] = {
        b_itos[0 * NHH + nh] + b_stos[0 * NHH + nh], b_itos[1 * NHH + nh] + b_stos[1 * NHH + nh],
        b_itos[2 * NHH + nh] + b_stos[2 * NHH + nh], b_itos[3 * NHH + nh] + b_stos[3 * NHH + nh]};
    const float* img_b = image + (size_t)b * NC * NS * NW;
    __syncthreads();
    for (int s = 0; s < NS; ++s) {
        float acc[4][16];
        #pragma unroll
        for (int g = 0; g < 4; ++g)
            #pragma unroll
            for (int j = 0; j < 16; ++j) acc[g][j] = bias[g];
        #pragma unroll 2
        for (int ci = 0; ci < NC; ++ci) {
            float imp[16], imc[16];
            const float* iprow = img_b + ((size_t)ci * NS + s) * NW + w0;
            #pragma unroll
            for (int qq = 0; qq < 4; ++qq) {
                float4 vv = *(const float4*)(iprow + 4 * qq);
                imc[4*qq] = vv.x; imc[4*qq+1] = vv.y; imc[4*qq+2] = vv.z; imc[4*qq+3] = vv.w;
            }
            if (s > 0) {
                #pragma unroll
                for (int qq = 0; qq < 4; ++qq) {
                    float4 vv = *(const float4*)(iprow - NW + 4 * qq);
                    imp[4*qq] = vv.x; imp[4*qq+1] = vv.y; imp[4*qq+2] = vv.z; imp[4*qq+3] = vv.w;
                }
            } else {
                #pragma unroll
                for (int j = 0; j < 16; ++j) imp[j] = 0.f;
            }
            float hv[18];
            #pragma unroll
            for (int j = 0; j < 18; ++j) hv[j] = h_lds[ci][w0 + j];
            const float* wip2 = w_itos + ((size_t)nh * NC + ci) * 3;
            const float* wsp2 = w_stos + ((size_t)nh * NHH + ci) * 3;
            #pragma unroll
            for (int g = 0; g < 4; ++g) {
                const float wi0 = wip2[(size_t)g * GSTR + 0], wi1 = wip2[(size_t)g * GSTR + 1];
                const float ws0 = wsp2[(size_t)g * GSTR + 0], ws1 = wsp2[(size_t)g * GSTR + 1],
                            ws2 = wsp2[(size_t)g * GSTR + 2];
                #pragma unroll
                for (int j = 0; j < 16; ++j)
                    acc[g][j] += wi0 * imp[j] + wi1 * imc[j] + ws0 * hv[j] + ws1 * hv[j+1] + ws2 * hv[j+2];
            }
        }
        float hn[16];
        #pragma unroll
        for (int j = 0; j < 16; ++j) {
            const float si = 1.f / (1.f + __expf(-acc[0][j]));
            const float tg = tanhf(acc[1][j]);
            const float sf = 1.f / (1.f + __expf(-acc[2][j]));
            const float so = 1.f / (1.f + __expf(-acc[3][j]));
            const float cold = c_r[j];
            c_r[j] = sf * cold + si * tg;
            hn[j] = cold * so;
        }
        __syncthreads();
        #pragma unroll
        for (int j = 0; j < 16; ++j) h_lds[nh][1 + w0 + j] = hn[j];
        float* opp = out + (((size_t)b * NHH + nh) * NS + s) * NW + w0;
        #pragma unroll
        for (int qq = 0; qq < 4; ++qq)
            *(float4*)(opp + 4 * qq) = make_float4(hn[4*qq], hn[4*qq+1], hn[4*qq+2], hn[4*qq+3]);
        __syncthreads();
    }
}

extern "C" void kernel_launch(void* const* d_in, const int* in_sizes, int n_in,
                              void* d_out, int out_size, void* d_ws, size_t ws_size,
                              hipStream_t stream) {
    const float* image  = (const float*)d_in[0];
    const float* w_itos = (const float*)d_in[1];
    const float* b_itos = (const float*)d_in[2];
    const float* w_stos = (const float*)d_in[3];
    const float* b_stos = (const float*)d_in[4];
    const float* h0     = (const float*)d_in[5];
    const float* c0     = (const float*)d_in[6];
    float* out = (float*)d_out;

    if (ws_size >= WS_NEEDED) {
        u16*      wip = (u16*)((char*)d_ws + WI_OFF);
        u16*      wsp = (u16*)((char*)d_ws + WS_OFF);
        unsigned* cnt = (unsigned*)((char*)d_ws + FLAG_OFF);
        u16*      hx  = (u16*)((char*)d_ws + HX_OFF);
        uint2*    fsp = (uint2*)((char*)d_ws + FS_OFF);
        hipMemsetAsync((char*)d_ws + FLAG_OFF, 0, 4096, stream);
        pack_weights<<<1280, 256, 0, stream>>>(w_itos, w_stos, wip, wsp);
        itos_gemm<<<1024, 512, 0, stream>>>(image, wip, b_itos, b_stos, fsp);
        rowlstm_ls<<<64, 512, 0, stream>>>(wsp, fsp, h0, c0, cnt, hx, out);
    } else {
        rowlstm_f32<<<NB, 512, 0, stream>>>(image, w_itos, b_itos, w_stos, b_stos, h0, c0, out);
    }
}